// Round 17
// baseline (5731.966 us; speedup 1.0000x reference)
//
#include <hip/hip_runtime.h>
#include <math.h>

// NeuroRNN: I = 0.8 I + 0.2 (Wrec r + Win x_t); r = 0.9 r + 0.1 tanh(I); out = Wout r
// B=32, T=2048, IN=256, H=1024, OUT=128 (all fp32)
//
// R17 = R15 (best, 5.50 ms) + EARLY PUBLISH DRAIN:
//  - The publish store was fire-and-forget; with in-order vmcnt retirement,
//    nothing forced it to complete until the producer's NEXT-step vmcnt(0) ->
//    the store could drain a full step late, and consumers spin on producer
//    drain laziness (explains R13's 2.26us phases, R16's null).
//  - Fix: s_waitcnt vmcnt(0) immediately after the publish store. Producer
//    stalls ~one store-ack mid-step (overlapping off-critical-path work);
//    consumers see tagged data ~1us earlier. Pre-issued sweep still floats
//    across barrier B (issued after the drain).
// Everything else identical to R15: MFMA compute (Wrec 32x + Win 8x on waves
// 0,1; Wout on wave 2), bf16 tag-in-data exchange over MALL (sc0 sc1), raw
// barriers (lgkmcnt-only at A), v_perm x-packing.

#define T_STEPS 2048
#define IN_SZ 256
#define H_SZ 1024
#define OUT_SZ 128
#define WGS 256
#define NWG 256
#define PB_WORDS 16384                 // dwords per dbuf half: 32 batch x 512
#define WS_WORDS (2 * PB_WORDS)

typedef unsigned int u32;
typedef u32 u32x2 __attribute__((ext_vector_type(2)));
typedef u32 u32x4 __attribute__((ext_vector_type(4)));
typedef float f32x4 __attribute__((ext_vector_type(4)));
typedef short s16x8 __attribute__((ext_vector_type(8)));

// init: tag bit = 1 (expected tag for "step -1"), bf16 halves ~= 0
__global__ void nrnn_init_ws(u32* __restrict__ ws) {
  const int i = blockIdx.x * blockDim.x + threadIdx.x;
  if (i < WS_WORDS) ws[i] = 0x00000001u;
}

__device__ __forceinline__ u32 bf16r(float v) {  // round-to-nearest-even bf16
  const u32 b = __float_as_uint(v);
  return (b + 0x7FFFu + ((b >> 16) & 1u)) >> 16;
}
__device__ __forceinline__ float tanh_fast(float v) {
  const float cx = fminf(fmaxf(v, -15.f), 15.f);
  const float e = __expf(2.f * cx);
  return (e - 1.f) * __builtin_amdgcn_rcpf(e + 1.f);
}

__global__ void __launch_bounds__(WGS, 1)
nrnn_main(const float* __restrict__ x, const float* __restrict__ Win,
          const float* __restrict__ Wrec, const float* __restrict__ Wout,
          float* __restrict__ out, float* __restrict__ ws) {
  const int tid = (int)threadIdx.x;
  const int wv  = tid >> 6;   // wave: 0,1 = Wrec+Win MFMA; 2 = Wout MFMA; 3 = aux
  const int ln  = tid & 63;   // lane in wave
  const int bg  = (int)blockIdx.x & 7;   // batch group (batches [4bg,4bg+4))
  const int jb  = (int)blockIdx.x >> 3;  // h-slice [32jb, 32jb+32)
  const int b0  = bg * 4;

  u32* pbuf = (u32*)ws;
  __shared__ __align__(16) char r_lds[8192];  // bf16 r [4 batch][1024 k], swizzled

  // ---- Wrec/Wout A-fragments -> VGPRs (static bf16, R9-proven layout) ----
  s16x8 wfrag[32];
  {
    const int g = (ln >> 4) & 3;
    const float* wp;
    if (wv < 2)       wp = Wrec + (size_t)(jb * 32 + wv * 16 + (ln & 15)) * H_SZ;
    else if (wv == 2) wp = Wout + (size_t)(jb * 4 + (ln & 3)) * H_SZ;
    else              wp = Wrec;  // wave 3: content unused
    #pragma unroll
    for (int st = 0; st < 32; ++st) {
      const int k0 = st * 32 + g * 8;
      const float4 c0 = *(const float4*)(wp + k0);
      const float4 c1 = *(const float4*)(wp + k0 + 4);
      s16x8 w;
      w[0] = (short)bf16r(c0.x); w[1] = (short)bf16r(c0.y);
      w[2] = (short)bf16r(c0.z); w[3] = (short)bf16r(c0.w);
      w[4] = (short)bf16r(c1.x); w[5] = (short)bf16r(c1.y);
      w[6] = (short)bf16r(c1.z); w[7] = (short)bf16r(c1.w);
      wfrag[st] = w;
    }
  }

  // ---- Win A-fragments (waves 0,1; same rows as their Wrec rows) ----
  s16x8 wifrag[8];
  if (wv < 2) {
    const float* wp = Win + (size_t)(jb * 32 + wv * 16 + (ln & 15)) * IN_SZ
                      + ((ln >> 4) & 3) * 8;
    #pragma unroll
    for (int ch = 0; ch < 8; ++ch) {
      const float4 c0 = *(const float4*)(wp + ch * 32);
      const float4 c1 = *(const float4*)(wp + ch * 32 + 4);
      s16x8 w;
      w[0] = (short)bf16r(c0.x); w[1] = (short)bf16r(c0.y);
      w[2] = (short)bf16r(c0.z); w[3] = (short)bf16r(c0.w);
      w[4] = (short)bf16r(c1.x); w[5] = (short)bf16r(c1.y);
      w[6] = (short)bf16r(c1.z); w[7] = (short)bf16r(c1.w);
      wifrag[ch] = w;
    }
  } else {
    const s16x8 z = {0, 0, 0, 0, 0, 0, 0, 0};
    #pragma unroll
    for (int ch = 0; ch < 8; ++ch) wifrag[ch] = z;
  }

  // x loader (B-frag slots: col=batch=ln&3, k=(ln>>4)*8 within each 32-chunk)
  auto ldx_issue = [&](int tt, float4 (&xv)[16]) {
    if (wv < 2) {
      const float* xb = x + ((size_t)(b0 + (ln & 3)) * T_STEPS + (size_t)tt) * IN_SZ
                        + ((ln >> 4) & 3) * 8;
      #pragma unroll
      for (int ch = 0; ch < 8; ++ch) {
        xv[2 * ch]     = *(const float4*)(xb + ch * 32);
        xv[2 * ch + 1] = *(const float4*)(xb + ch * 32 + 4);
      }
    }
  };
  // fp32 -> packed bf16 (RTZ via v_perm: dst = hi16(a)<<16 | hi16(b))
  auto cvt = [&](const float4 (&xv)[16], u32x4 (&xf)[8]) {
    if (wv < 2) {
      #pragma unroll
      for (int ch = 0; ch < 8; ++ch) {
        u32x4 u;
        u[0] = __builtin_amdgcn_perm(__float_as_uint(xv[2 * ch].y),
                                     __float_as_uint(xv[2 * ch].x), 0x07060302u);
        u[1] = __builtin_amdgcn_perm(__float_as_uint(xv[2 * ch].w),
                                     __float_as_uint(xv[2 * ch].z), 0x07060302u);
        u[2] = __builtin_amdgcn_perm(__float_as_uint(xv[2 * ch + 1].y),
                                     __float_as_uint(xv[2 * ch + 1].x), 0x07060302u);
        u[3] = __builtin_amdgcn_perm(__float_as_uint(xv[2 * ch + 1].w),
                                     __float_as_uint(xv[2 * ch + 1].z), 0x07060302u);
        xf[ch] = u;
      }
    }
  };

  // ---- persistent state (publishing lanes of waves 0,1) ----
  float Ist[4] = {0.f, 0.f, 0.f, 0.f};
  float rloc[4] = {0.f, 0.f, 0.f, 0.f};

  // ---- prologue: x(0) -> xf; pre-issue sweep for t=0 (buffer 1, tag 1) ----
  u32x4 xf[8];
  {
    float4 xv0[16];
    ldx_issue(0, xv0);
    cvt(xv0, xf);
  }
  u32x4 swa, swb;
  {
    const u32* sp0 = pbuf + (size_t)PB_WORDS + (size_t)bg * 2048 + 4 * tid;
    asm volatile("global_load_dwordx4 %0, %2, off sc0 sc1\n\t"
                 "global_load_dwordx4 %1, %3, off sc0 sc1"
                 : "=v"(swa), "=v"(swb) : "v"(sp0), "v"(sp0 + 1024) : "memory");
  }

  for (int t = 0; t < T_STEPS; ++t) {
    // ---- finish pre-issued sweep; retry until all tags match (R12 poll) ----
    const u32 etag = (((u32)(t - 1)) >> 1) & 1u;
    const u32* sp0 = pbuf + (size_t)((t + 1) & 1) * PB_WORDS + (size_t)bg * 2048 + 4 * tid;
    asm volatile("s_waitcnt vmcnt(0)" : "+v"(swa), "+v"(swb) :: "memory");
    for (;;) {
      u32 bad = 0;
      #pragma unroll
      for (int i = 0; i < 4; ++i) { bad |= swa[i] ^ etag; bad |= swb[i] ^ etag; }
      if (!__any(bad & 1u)) break;
      asm volatile("global_load_dwordx4 %0, %2, off sc0 sc1\n\t"
                   "global_load_dwordx4 %1, %3, off sc0 sc1\n\t"
                   "s_waitcnt vmcnt(0)"
                   : "=&v"(swa), "=&v"(swb) : "v"(sp0), "v"(sp0 + 1024) : "memory");
    }
    // ---- stage to swizzled LDS (R9-proven, conflict-free) ----
    {
      const int bi0 = tid >> 7, bi1 = 2 + bi0;
      *(u32x4*)(r_lds + ((16 * tid) ^ ((bi0 & 3) << 4) ^ ((bi0 & 1) << 6))) = swa;
      *(u32x4*)(r_lds + ((4096 + 16 * tid) ^ ((bi1 & 3) << 4) ^ ((bi1 & 1) << 6))) = swb;
    }

    // ---- barrier A (raw): LDS-write visibility only, NO vmcnt drain ----
    asm volatile("s_waitcnt lgkmcnt(0)" ::: "memory");
    __builtin_amdgcn_s_barrier();
    __builtin_amdgcn_sched_barrier(0);

    // ---- issue x(t+1) loads (latency hides under MFMA/publish below) ----
    float4 xv[16];
    ldx_issue((t + 1 < T_STEPS) ? t + 1 : t, xv);

    // ---- Wrec / Wout MFMA over K=1024, dual accumulator chains ----
    f32x4 acc = {0.f, 0.f, 0.f, 0.f};
    if (wv <= 2) {
      const int beff = ln & 3;
      const int g16 = ((ln >> 4) & 3) * 16;
      const int bswz = ((beff & 3) << 4) | ((beff & 1) << 6);
      const char* rb = r_lds + beff * 2048;
      f32x4 a0 = {0.f, 0.f, 0.f, 0.f}, a1 = {0.f, 0.f, 0.f, 0.f};
      #pragma unroll
      for (int st = 0; st < 32; st += 2) {
        const s16x8 bfa = *(const s16x8*)(rb + ((st * 64 + g16) ^ bswz));
        const s16x8 bfb = *(const s16x8*)(rb + (((st + 1) * 64 + g16) ^ bswz));
        a0 = __builtin_amdgcn_mfma_f32_16x16x32_bf16(wfrag[st], bfa, a0, 0, 0, 0);
        a1 = __builtin_amdgcn_mfma_f32_16x16x32_bf16(wfrag[st + 1], bfb, a1, 0, 0, 0);
      }
      acc = a0 + a1;
    }

    // ---- Win*x via MFMA (waves 0,1; same C layout as acc) ----
    f32x4 wm = {0.f, 0.f, 0.f, 0.f};
    if (wv < 2) {
      #pragma unroll
      for (int ch = 0; ch < 8; ++ch)
        wm = __builtin_amdgcn_mfma_f32_16x16x32_bf16(wifrag[ch],
                                                     *(const s16x8*)&xf[ch], wm, 0, 0, 0);
    }

    // ---- I update; tanh; tagged bf16 publish + EARLY DRAIN ----
    if (wv < 2 && (ln & 12) == 0) {
      const int b = ln & 3, g4 = ln >> 4;
      const u32 ptag = (((u32)t) >> 1) & 1u;
      const float I0 = fmaf(0.2f, acc[0] + wm[0], 0.8f * Ist[0]);
      const float I1 = fmaf(0.2f, acc[1] + wm[1], 0.8f * Ist[1]);
      const float I2 = fmaf(0.2f, acc[2] + wm[2], 0.8f * Ist[2]);
      const float I3 = fmaf(0.2f, acc[3] + wm[3], 0.8f * Ist[3]);
      Ist[0] = I0; Ist[1] = I1; Ist[2] = I2; Ist[3] = I3;
      rloc[0] = fmaf(0.1f, tanh_fast(I0), 0.9f * rloc[0]);
      rloc[1] = fmaf(0.1f, tanh_fast(I1), 0.9f * rloc[1]);
      rloc[2] = fmaf(0.1f, tanh_fast(I2), 0.9f * rloc[2]);
      rloc[3] = fmaf(0.1f, tanh_fast(I3), 0.9f * rloc[3]);
      u32x2 pk;
      pk[0] = (((bf16r(rloc[1]) << 16) | (bf16r(rloc[0]) & 0xFFFFu)) & ~1u) | ptag;
      pk[1] = (((bf16r(rloc[3]) << 16) | (bf16r(rloc[2]) & 0xFFFFu)) & ~1u) | ptag;
      u32* pw = pbuf + (size_t)(t & 1) * PB_WORDS + (size_t)(b0 + b) * 512
                + jb * 16 + wv * 8 + g4 * 2;
      asm volatile("global_store_dwordx2 %0, %1, off sc0 sc1"
                   :: "v"(pw), "v"(pk) : "memory");
      // EARLY DRAIN: force the publish to MALL NOW (not at next step's poll).
      // Producers stall ~one store-ack here, overlapping off-critical work;
      // consumers see the tag up to ~1us earlier.
      asm volatile("s_waitcnt vmcnt(0)" ::: "memory");
    }

    // ---- wave 2: out_{t-1} = Wout r_{t-1} (one float4 store) ----
    if (wv == 2 && ln < 4 && t > 0) {
      float4 o; o.x = acc[0]; o.y = acc[1]; o.z = acc[2]; o.w = acc[3];
      *(float4*)(out + ((size_t)(b0 + ln) * T_STEPS + (size_t)(t - 1)) * OUT_SZ
                 + jb * 4) = o;
    }

    // ---- convert x(t+1) -> xf (x loads have landed under the work above) ----
    cvt(xv, xf);

    // ---- pre-issue sweep for t+1 (buffer t&1); dangles ONLY across barrier B ----
    {
      const u32* np0 = pbuf + (size_t)(t & 1) * PB_WORDS + (size_t)bg * 2048 + 4 * tid;
      asm volatile("global_load_dwordx4 %0, %2, off sc0 sc1\n\t"
                   "global_load_dwordx4 %1, %3, off sc0 sc1"
                   : "=v"(swa), "=v"(swb) : "v"(np0), "v"(np0 + 1024) : "memory");
    }

    // ---- barrier B (raw): read-before-overwrite ordering only, NO drains ----
    __builtin_amdgcn_sched_barrier(0);
    __builtin_amdgcn_s_barrier();
    __builtin_amdgcn_sched_barrier(0);
  }

  // ---- epilogue: out(T-1); pre-issued sweep targets buffer 1, etag 1 ----
  {
    const u32 etag = (((u32)(T_STEPS - 1)) >> 1) & 1u;
    const u32* sp0 = pbuf + (size_t)PB_WORDS + (size_t)bg * 2048 + 4 * tid;
    asm volatile("s_waitcnt vmcnt(0)" : "+v"(swa), "+v"(swb) :: "memory");
    for (;;) {
      u32 bad = 0;
      #pragma unroll
      for (int i = 0; i < 4; ++i) { bad |= swa[i] ^ etag; bad |= swb[i] ^ etag; }
      if (!__any(bad & 1u)) break;
      asm volatile("global_load_dwordx4 %0, %2, off sc0 sc1\n\t"
                   "global_load_dwordx4 %1, %3, off sc0 sc1\n\t"
                   "s_waitcnt vmcnt(0)"
                   : "=&v"(swa), "=&v"(swb) : "v"(sp0), "v"(sp0 + 1024) : "memory");
    }
    const int bi0 = tid >> 7, bi1 = 2 + bi0;
    *(u32x4*)(r_lds + ((16 * tid) ^ ((bi0 & 3) << 4) ^ ((bi0 & 1) << 6))) = swa;
    *(u32x4*)(r_lds + ((4096 + 16 * tid) ^ ((bi1 & 3) << 4) ^ ((bi1 & 1) << 6))) = swb;
  }
  __syncthreads();
  if (wv == 2) {
    const int beff = ln & 3;
    const int g16 = ((ln >> 4) & 3) * 16;
    const int bswz = ((beff & 3) << 4) | ((beff & 1) << 6);
    const char* rb = r_lds + beff * 2048;
    f32x4 acc = {0.f, 0.f, 0.f, 0.f};
    #pragma unroll
    for (int st = 0; st < 32; ++st) {
      const s16x8 bf = *(const s16x8*)(rb + ((st * 64 + g16) ^ bswz));
      acc = __builtin_amdgcn_mfma_f32_16x16x32_bf16(wfrag[st], bf, acc, 0, 0, 0);
    }
    if (ln < 4) {
      float4 o; o.x = acc[0]; o.y = acc[1]; o.z = acc[2]; o.w = acc[3];
      *(float4*)(out + ((size_t)(b0 + ln) * T_STEPS + (size_t)(T_STEPS - 1)) * OUT_SZ
                 + jb * 4) = o;
    }
  }
}

extern "C" void kernel_launch(void* const* d_in, const int* in_sizes, int n_in,
                              void* d_out, int out_size, void* d_ws, size_t ws_size,
                              hipStream_t stream) {
  const float* xp    = (const float*)d_in[0];
  const float* winp  = (const float*)d_in[1];
  const float* wrecp = (const float*)d_in[2];
  const float* woutp = (const float*)d_in[3];
  float* outp = (float*)d_out;
  float* wsp  = (float*)d_ws;

  // re-init packed r buffers to tag=1 / value~0 every call (graph-replay safe)
  nrnn_init_ws<<<(WS_WORDS + 255) / 256, 256, 0, stream>>>((u32*)d_ws);

  nrnn_main<<<dim3(NWG), dim3(WGS), 0, stream>>>(xp, winp, wrecp, woutp, outp, wsp);
}

// Round 19
// 5512.391 us; speedup vs baseline: 1.0398x; 1.0398x over previous
//
#include <hip/hip_runtime.h>
#include <math.h>

// NeuroRNN: I = 0.8 I + 0.2 (Wrec r + Win x_t); r = 0.9 r + 0.1 tanh(I); out = Wout r
// B=32, T=2048, IN=256, H=1024, OUT=128 (all fp32)
//
// R19 = R15 restored byte-for-byte (best passing, 5.50 ms). R13-R18 falsified
// every remaining handoff lever (two-stream x2, pipelined poll, early drain,
// barrier-drain removal, L2-local exchange x3 incl. one deadlock and one HSA
// abort): the ~2.0us/step MALL communication cycle (publish flight + cross-die
// visibility + poll) is the structural floor for this strictly-sequential
// T=2048 recurrence on non-coherent-L2 chiplets.
//
// Structure: 256 WGs x 256 thr; WG (bg=blk&7, jb=blk>>3) owns batches
// [4bg,4bg+4) x h-rows [32jb,+32). Waves 0,1: Wrec (32 MFMA) + Win (8 MFMA)
// with static bf16 A-frags in VGPRs; wave 2: Wout MFMA + out store. Exchange:
// self-validating bf16 r with dword-LSB step tag over MALL (sc0 sc1), one
// fire-and-forget publish + one pre-issued poll sweep per step; raw barriers
// (lgkmcnt-only at A, none at B); v_perm x-packing; swizzled LDS staging.

#define T_STEPS 2048
#define IN_SZ 256
#define H_SZ 1024
#define OUT_SZ 128
#define WGS 256
#define NWG 256
#define PB_WORDS 16384                 // dwords per dbuf half: 32 batch x 512
#define WS_WORDS (2 * PB_WORDS)

typedef unsigned int u32;
typedef u32 u32x2 __attribute__((ext_vector_type(2)));
typedef u32 u32x4 __attribute__((ext_vector_type(4)));
typedef float f32x4 __attribute__((ext_vector_type(4)));
typedef short s16x8 __attribute__((ext_vector_type(8)));

// init: tag bit = 1 (expected tag for "step -1"), bf16 halves ~= 0
__global__ void nrnn_init_ws(u32* __restrict__ ws) {
  const int i = blockIdx.x * blockDim.x + threadIdx.x;
  if (i < WS_WORDS) ws[i] = 0x00000001u;
}

__device__ __forceinline__ u32 bf16r(float v) {  // round-to-nearest-even bf16
  const u32 b = __float_as_uint(v);
  return (b + 0x7FFFu + ((b >> 16) & 1u)) >> 16;
}
__device__ __forceinline__ float tanh_fast(float v) {
  const float cx = fminf(fmaxf(v, -15.f), 15.f);
  const float e = __expf(2.f * cx);
  return (e - 1.f) * __builtin_amdgcn_rcpf(e + 1.f);
}

__global__ void __launch_bounds__(WGS, 1)
nrnn_main(const float* __restrict__ x, const float* __restrict__ Win,
          const float* __restrict__ Wrec, const float* __restrict__ Wout,
          float* __restrict__ out, float* __restrict__ ws) {
  const int tid = (int)threadIdx.x;
  const int wv  = tid >> 6;   // wave: 0,1 = Wrec+Win MFMA; 2 = Wout MFMA; 3 = aux
  const int ln  = tid & 63;   // lane in wave
  const int bg  = (int)blockIdx.x & 7;   // batch group (batches [4bg,4bg+4))
  const int jb  = (int)blockIdx.x >> 3;  // h-slice [32jb, 32jb+32)
  const int b0  = bg * 4;

  u32* pbuf = (u32*)ws;
  __shared__ __align__(16) char r_lds[8192];  // bf16 r [4 batch][1024 k], swizzled

  // ---- Wrec/Wout A-fragments -> VGPRs (static bf16, R9-proven layout) ----
  s16x8 wfrag[32];
  {
    const int g = (ln >> 4) & 3;
    const float* wp;
    if (wv < 2)       wp = Wrec + (size_t)(jb * 32 + wv * 16 + (ln & 15)) * H_SZ;
    else if (wv == 2) wp = Wout + (size_t)(jb * 4 + (ln & 3)) * H_SZ;
    else              wp = Wrec;  // wave 3: content unused
    #pragma unroll
    for (int st = 0; st < 32; ++st) {
      const int k0 = st * 32 + g * 8;
      const float4 c0 = *(const float4*)(wp + k0);
      const float4 c1 = *(const float4*)(wp + k0 + 4);
      s16x8 w;
      w[0] = (short)bf16r(c0.x); w[1] = (short)bf16r(c0.y);
      w[2] = (short)bf16r(c0.z); w[3] = (short)bf16r(c0.w);
      w[4] = (short)bf16r(c1.x); w[5] = (short)bf16r(c1.y);
      w[6] = (short)bf16r(c1.z); w[7] = (short)bf16r(c1.w);
      wfrag[st] = w;
    }
  }

  // ---- Win A-fragments (waves 0,1; same rows as their Wrec rows) ----
  s16x8 wifrag[8];
  if (wv < 2) {
    const float* wp = Win + (size_t)(jb * 32 + wv * 16 + (ln & 15)) * IN_SZ
                      + ((ln >> 4) & 3) * 8;
    #pragma unroll
    for (int ch = 0; ch < 8; ++ch) {
      const float4 c0 = *(const float4*)(wp + ch * 32);
      const float4 c1 = *(const float4*)(wp + ch * 32 + 4);
      s16x8 w;
      w[0] = (short)bf16r(c0.x); w[1] = (short)bf16r(c0.y);
      w[2] = (short)bf16r(c0.z); w[3] = (short)bf16r(c0.w);
      w[4] = (short)bf16r(c1.x); w[5] = (short)bf16r(c1.y);
      w[6] = (short)bf16r(c1.z); w[7] = (short)bf16r(c1.w);
      wifrag[ch] = w;
    }
  } else {
    const s16x8 z = {0, 0, 0, 0, 0, 0, 0, 0};
    #pragma unroll
    for (int ch = 0; ch < 8; ++ch) wifrag[ch] = z;
  }

  // x loader (B-frag slots: col=batch=ln&3, k=(ln>>4)*8 within each 32-chunk)
  auto ldx_issue = [&](int tt, float4 (&xv)[16]) {
    if (wv < 2) {
      const float* xb = x + ((size_t)(b0 + (ln & 3)) * T_STEPS + (size_t)tt) * IN_SZ
                        + ((ln >> 4) & 3) * 8;
      #pragma unroll
      for (int ch = 0; ch < 8; ++ch) {
        xv[2 * ch]     = *(const float4*)(xb + ch * 32);
        xv[2 * ch + 1] = *(const float4*)(xb + ch * 32 + 4);
      }
    }
  };
  // fp32 -> packed bf16 (RTZ via v_perm: dst = hi16(a)<<16 | hi16(b))
  auto cvt = [&](const float4 (&xv)[16], u32x4 (&xf)[8]) {
    if (wv < 2) {
      #pragma unroll
      for (int ch = 0; ch < 8; ++ch) {
        u32x4 u;
        u[0] = __builtin_amdgcn_perm(__float_as_uint(xv[2 * ch].y),
                                     __float_as_uint(xv[2 * ch].x), 0x07060302u);
        u[1] = __builtin_amdgcn_perm(__float_as_uint(xv[2 * ch].w),
                                     __float_as_uint(xv[2 * ch].z), 0x07060302u);
        u[2] = __builtin_amdgcn_perm(__float_as_uint(xv[2 * ch + 1].y),
                                     __float_as_uint(xv[2 * ch + 1].x), 0x07060302u);
        u[3] = __builtin_amdgcn_perm(__float_as_uint(xv[2 * ch + 1].w),
                                     __float_as_uint(xv[2 * ch + 1].z), 0x07060302u);
        xf[ch] = u;
      }
    }
  };

  // ---- persistent state (publishing lanes of waves 0,1) ----
  float Ist[4] = {0.f, 0.f, 0.f, 0.f};
  float rloc[4] = {0.f, 0.f, 0.f, 0.f};

  // ---- prologue: x(0) -> xf; pre-issue sweep for t=0 (buffer 1, tag 1) ----
  u32x4 xf[8];
  {
    float4 xv0[16];
    ldx_issue(0, xv0);
    cvt(xv0, xf);
  }
  u32x4 swa, swb;
  {
    const u32* sp0 = pbuf + (size_t)PB_WORDS + (size_t)bg * 2048 + 4 * tid;
    asm volatile("global_load_dwordx4 %0, %2, off sc0 sc1\n\t"
                 "global_load_dwordx4 %1, %3, off sc0 sc1"
                 : "=v"(swa), "=v"(swb) : "v"(sp0), "v"(sp0 + 1024) : "memory");
  }

  for (int t = 0; t < T_STEPS; ++t) {
    // ---- finish pre-issued sweep; retry until all tags match (R12 poll) ----
    const u32 etag = (((u32)(t - 1)) >> 1) & 1u;
    const u32* sp0 = pbuf + (size_t)((t + 1) & 1) * PB_WORDS + (size_t)bg * 2048 + 4 * tid;
    asm volatile("s_waitcnt vmcnt(0)" : "+v"(swa), "+v"(swb) :: "memory");
    for (;;) {
      u32 bad = 0;
      #pragma unroll
      for (int i = 0; i < 4; ++i) { bad |= swa[i] ^ etag; bad |= swb[i] ^ etag; }
      if (!__any(bad & 1u)) break;
      asm volatile("global_load_dwordx4 %0, %2, off sc0 sc1\n\t"
                   "global_load_dwordx4 %1, %3, off sc0 sc1\n\t"
                   "s_waitcnt vmcnt(0)"
                   : "=&v"(swa), "=&v"(swb) : "v"(sp0), "v"(sp0 + 1024) : "memory");
    }
    // ---- stage to swizzled LDS (R9-proven, conflict-free) ----
    {
      const int bi0 = tid >> 7, bi1 = 2 + bi0;
      *(u32x4*)(r_lds + ((16 * tid) ^ ((bi0 & 3) << 4) ^ ((bi0 & 1) << 6))) = swa;
      *(u32x4*)(r_lds + ((4096 + 16 * tid) ^ ((bi1 & 3) << 4) ^ ((bi1 & 1) << 6))) = swb;
    }

    // ---- barrier A (raw): LDS-write visibility only, NO vmcnt drain ----
    asm volatile("s_waitcnt lgkmcnt(0)" ::: "memory");
    __builtin_amdgcn_s_barrier();
    __builtin_amdgcn_sched_barrier(0);

    // ---- issue x(t+1) loads (latency hides under MFMA/publish below) ----
    float4 xv[16];
    ldx_issue((t + 1 < T_STEPS) ? t + 1 : t, xv);

    // ---- Wrec / Wout MFMA over K=1024, dual accumulator chains ----
    f32x4 acc = {0.f, 0.f, 0.f, 0.f};
    if (wv <= 2) {
      const int beff = ln & 3;
      const int g16 = ((ln >> 4) & 3) * 16;
      const int bswz = ((beff & 3) << 4) | ((beff & 1) << 6);
      const char* rb = r_lds + beff * 2048;
      f32x4 a0 = {0.f, 0.f, 0.f, 0.f}, a1 = {0.f, 0.f, 0.f, 0.f};
      #pragma unroll
      for (int st = 0; st < 32; st += 2) {
        const s16x8 bfa = *(const s16x8*)(rb + ((st * 64 + g16) ^ bswz));
        const s16x8 bfb = *(const s16x8*)(rb + (((st + 1) * 64 + g16) ^ bswz));
        a0 = __builtin_amdgcn_mfma_f32_16x16x32_bf16(wfrag[st], bfa, a0, 0, 0, 0);
        a1 = __builtin_amdgcn_mfma_f32_16x16x32_bf16(wfrag[st + 1], bfb, a1, 0, 0, 0);
      }
      acc = a0 + a1;
    }

    // ---- Win*x via MFMA (waves 0,1; same C layout as acc) ----
    f32x4 wm = {0.f, 0.f, 0.f, 0.f};
    if (wv < 2) {
      #pragma unroll
      for (int ch = 0; ch < 8; ++ch)
        wm = __builtin_amdgcn_mfma_f32_16x16x32_bf16(wifrag[ch],
                                                     *(const s16x8*)&xf[ch], wm, 0, 0, 0);
    }

    // ---- I update; tanh; tagged bf16 publish (fire-and-forget dwordx2) ----
    if (wv < 2 && (ln & 12) == 0) {
      const int b = ln & 3, g4 = ln >> 4;
      const u32 ptag = (((u32)t) >> 1) & 1u;
      const float I0 = fmaf(0.2f, acc[0] + wm[0], 0.8f * Ist[0]);
      const float I1 = fmaf(0.2f, acc[1] + wm[1], 0.8f * Ist[1]);
      const float I2 = fmaf(0.2f, acc[2] + wm[2], 0.8f * Ist[2]);
      const float I3 = fmaf(0.2f, acc[3] + wm[3], 0.8f * Ist[3]);
      Ist[0] = I0; Ist[1] = I1; Ist[2] = I2; Ist[3] = I3;
      rloc[0] = fmaf(0.1f, tanh_fast(I0), 0.9f * rloc[0]);
      rloc[1] = fmaf(0.1f, tanh_fast(I1), 0.9f * rloc[1]);
      rloc[2] = fmaf(0.1f, tanh_fast(I2), 0.9f * rloc[2]);
      rloc[3] = fmaf(0.1f, tanh_fast(I3), 0.9f * rloc[3]);
      u32x2 pk;
      pk[0] = (((bf16r(rloc[1]) << 16) | (bf16r(rloc[0]) & 0xFFFFu)) & ~1u) | ptag;
      pk[1] = (((bf16r(rloc[3]) << 16) | (bf16r(rloc[2]) & 0xFFFFu)) & ~1u) | ptag;
      u32* pw = pbuf + (size_t)(t & 1) * PB_WORDS + (size_t)(b0 + b) * 512
                + jb * 16 + wv * 8 + g4 * 2;
      asm volatile("global_store_dwordx2 %0, %1, off sc0 sc1"
                   :: "v"(pw), "v"(pk) : "memory");
    }

    // ---- wave 2: out_{t-1} = Wout r_{t-1} (one float4 store) ----
    if (wv == 2 && ln < 4 && t > 0) {
      float4 o; o.x = acc[0]; o.y = acc[1]; o.z = acc[2]; o.w = acc[3];
      *(float4*)(out + ((size_t)(b0 + ln) * T_STEPS + (size_t)(t - 1)) * OUT_SZ
                 + jb * 4) = o;
    }

    // ---- convert x(t+1) -> xf (x loads have landed under the work above) ----
    cvt(xv, xf);

    // ---- pre-issue sweep for t+1 (buffer t&1); dangles ONLY across barrier B ----
    {
      const u32* np0 = pbuf + (size_t)(t & 1) * PB_WORDS + (size_t)bg * 2048 + 4 * tid;
      asm volatile("global_load_dwordx4 %0, %2, off sc0 sc1\n\t"
                   "global_load_dwordx4 %1, %3, off sc0 sc1"
                   : "=v"(swa), "=v"(swb) : "v"(np0), "v"(np0 + 1024) : "memory");
    }

    // ---- barrier B (raw): read-before-overwrite ordering only, NO drains ----
    __builtin_amdgcn_sched_barrier(0);
    __builtin_amdgcn_s_barrier();
    __builtin_amdgcn_sched_barrier(0);
  }

  // ---- epilogue: out(T-1); pre-issued sweep targets buffer 1, etag 1 ----
  {
    const u32 etag = (((u32)(T_STEPS - 1)) >> 1) & 1u;
    const u32* sp0 = pbuf + (size_t)PB_WORDS + (size_t)bg * 2048 + 4 * tid;
    asm volatile("s_waitcnt vmcnt(0)" : "+v"(swa), "+v"(swb) :: "memory");
    for (;;) {
      u32 bad = 0;
      #pragma unroll
      for (int i = 0; i < 4; ++i) { bad |= swa[i] ^ etag; bad |= swb[i] ^ etag; }
      if (!__any(bad & 1u)) break;
      asm volatile("global_load_dwordx4 %0, %2, off sc0 sc1\n\t"
                   "global_load_dwordx4 %1, %3, off sc0 sc1\n\t"
                   "s_waitcnt vmcnt(0)"
                   : "=&v"(swa), "=&v"(swb) : "v"(sp0), "v"(sp0 + 1024) : "memory");
    }
    const int bi0 = tid >> 7, bi1 = 2 + bi0;
    *(u32x4*)(r_lds + ((16 * tid) ^ ((bi0 & 3) << 4) ^ ((bi0 & 1) << 6))) = swa;
    *(u32x4*)(r_lds + ((4096 + 16 * tid) ^ ((bi1 & 3) << 4) ^ ((bi1 & 1) << 6))) = swb;
  }
  __syncthreads();
  if (wv == 2) {
    const int beff = ln & 3;
    const int g16 = ((ln >> 4) & 3) * 16;
    const int bswz = ((beff & 3) << 4) | ((beff & 1) << 6);
    const char* rb = r_lds + beff * 2048;
    f32x4 acc = {0.f, 0.f, 0.f, 0.f};
    #pragma unroll
    for (int st = 0; st < 32; ++st) {
      const s16x8 bf = *(const s16x8*)(rb + ((st * 64 + g16) ^ bswz));
      acc = __builtin_amdgcn_mfma_f32_16x16x32_bf16(wfrag[st], bf, acc, 0, 0, 0);
    }
    if (ln < 4) {
      float4 o; o.x = acc[0]; o.y = acc[1]; o.z = acc[2]; o.w = acc[3];
      *(float4*)(out + ((size_t)(b0 + ln) * T_STEPS + (size_t)(T_STEPS - 1)) * OUT_SZ
                 + jb * 4) = o;
    }
  }
}

extern "C" void kernel_launch(void* const* d_in, const int* in_sizes, int n_in,
                              void* d_out, int out_size, void* d_ws, size_t ws_size,
                              hipStream_t stream) {
  const float* xp    = (const float*)d_in[0];
  const float* winp  = (const float*)d_in[1];
  const float* wrecp = (const float*)d_in[2];
  const float* woutp = (const float*)d_in[3];
  float* outp = (float*)d_out;
  float* wsp  = (float*)d_ws;

  // re-init packed r buffers to tag=1 / value~0 every call (graph-replay safe)
  nrnn_init_ws<<<(WS_WORDS + 255) / 256, 256, 0, stream>>>((u32*)d_ws);

  nrnn_main<<<dim3(NWG), dim3(WGS), 0, stream>>>(xp, winp, wrecp, woutp, outp, wsp);
}